// Round 9
// baseline (214.946 us; speedup 1.0000x reference)
//
#include <hip/hip_runtime.h>
#include <math.h>

#define B_ 512
#define C_ 100
#define E_ 2048
#define F_ 128

typedef _Float16 f16x8 __attribute__((ext_vector_type(8)));
typedef _Float16 f16x2 __attribute__((ext_vector_type(2)));
typedef float    f32x4 __attribute__((ext_vector_type(4)));

#define AS1q __attribute__((address_space(1)))
#define AS3q __attribute__((address_space(3)))

// async global->LDS DMA, 16 B per lane; LDS dest = wave-uniform base + lane*16
__device__ __forceinline__ void gl_lds16(const void* g, void* lds_base) {
    __builtin_amdgcn_global_load_lds((const AS1q void*)g, (AS3q void*)lds_base, 16, 0, 0);
}

// ---------------- kernel 1: PURE-STREAM W fp32 -> Wh fp16 + v = W^T u
// (round-7 redesign: old k_gram was ~56 us vs 27 us floor — 4-way-conflict A1
//  column reads + 16B-scattered Wh stores + 4 barriers/block. This version:
//  lane owns a COLUMN PAIR, loops over rows; v accumulates in registers.
//  Zero LDS, zero barriers, zero bank conflicts, coalesced loads AND stores.
//  y = W v moves into k_main as MFMA reusing staged fragments.)
// blocks 0..399: c = b>>2, col-window = (b&3)*512; wave w owns 128 cols,
//                lane owns cols base+2l, base+2l+1.
// blocks 400..431: x fp32 -> fp16 xh.
__global__ __launch_bounds__(256, 4)
void k_conv(const float* __restrict__ W, _Float16* __restrict__ Wh,
            const float* __restrict__ x, _Float16* __restrict__ xh,
            const float* __restrict__ u, float* __restrict__ v) {
    const int b = blockIdx.x;
    const int t = threadIdx.x;

    if (b >= 400) {   // ---- x conversion
        const size_t base = (size_t)(b - 400) * 32768 + t * 8;
#pragma unroll
        for (int it = 0; it < 16; ++it) {
            const size_t idx = base + (size_t)it * 2048;
            float4 a  = *(const float4*)(x + idx);
            float4 bb = *(const float4*)(x + idx + 4);
            f16x8 h;
            h[0] = (_Float16)a.x;  h[1] = (_Float16)a.y;  h[2] = (_Float16)a.z;  h[3] = (_Float16)a.w;
            h[4] = (_Float16)bb.x; h[5] = (_Float16)bb.y; h[6] = (_Float16)bb.z; h[7] = (_Float16)bb.w;
            *(f16x8*)(xh + idx) = h;
        }
        return;
    }

    const int c   = b >> 2;
    const int col = (b & 3) * 512 + (t >> 6) * 128 + (t & 63) * 2;

    const float* wsrc = W  + (size_t)c * F_ * E_ + col;
    _Float16*    wdst = Wh + (size_t)c * F_ * E_ + col;
    const float* uc   = u  + (size_t)c * F_;

    float v0 = 0.f, v1 = 0.f;

    // 16 x 8-row chunks: 8 float2 loads in flight (MLP), then cvt+store+fma
    for (int r8 = 0; r8 < 16; ++r8) {
        float2 wv[8];
        float  ub[8];
#pragma unroll
        for (int j = 0; j < 8; ++j) {
            const int r = r8 * 8 + j;
            wv[j] = *(const float2*)(wsrc + (size_t)r * E_);
            ub[j] = uc[r];                     // wave-uniform -> s_load
        }
#pragma unroll
        for (int j = 0; j < 8; ++j) {
            const int r = r8 * 8 + j;
            f16x2 h;
            h[0] = (_Float16)wv[j].x;
            h[1] = (_Float16)wv[j].y;
            *(f16x2*)(wdst + (size_t)r * E_) = h;
            v0 = fmaf(wv[j].x, ub[j], v0);
            v1 = fmaf(wv[j].y, ub[j], v1);
        }
    }
    *(float2*)(v + (size_t)c * E_ + col) = (float2){v0, v1};
}

// ---------------- kernel 2: fused fp16 MFMA GEMM + y=Wv + dist2 + exp
// Round-3 structure (best measured) + round-5's VERIFIED y-MFMA path:
//   preamble: v[c] (8 KB) -> Vs LDS.
//   K-loop: stage Xs/Ws (DMA) -> barrier -> 32 GEMM MFMA + 8 y-MFMA
//           (y_acc[nt] += bv[kh][nt] x vf, vf = v-window as B-col-0) -> barrier.
//   post-loop: y -> ys (col-0 lanes), rsig = sqrt(u.y / y.y), dist2+exp.
// XCD map (grid 416): xcd=bid&7, slot=bid>>3, c=xcd*13+(slot>>2), b0=(slot&3)*128
//   -> 4 sibling b-tiles of a class on ONE XCD -> Wh slice L2-shared.
// LDS 16+16+8+~1 = 41 KB -> 3 blocks/CU.
__global__ __launch_bounds__(256, 3)
void k_main(const _Float16* __restrict__ xh, const _Float16* __restrict__ Wh,
            const float* __restrict__ bias, const float* __restrict__ cent,
            const float* __restrict__ u, const float* __restrict__ v,
            float* __restrict__ out) {
    const int bid  = blockIdx.x;
    const int xcd  = bid & 7;
    const int slot = bid >> 3;
    const int c    = xcd * 13 + (slot >> 2);
    if (c >= C_) return;                       // uniform early-out (16 blocks)
    const int b0 = (slot & 3) * 128;

    const int t  = threadIdx.x;
    const int w  = t >> 6;
    const int l  = t & 63;
    const int wm = w & 1, wn = w >> 1;
    const int ln = l & 15, quad = l >> 4;

    __shared__ _Float16 Xs[128 * 64];   // 16 KB
    __shared__ _Float16 Ws[128 * 64];   // 16 KB
    __shared__ float    Vs[E_];         //  8 KB: v[c] resident for whole K-loop
    __shared__ float    ys[128];
    __shared__ float    red2[2][2];
    __shared__ float    s_rsig;

    // ---- preamble: v[c] -> LDS (ordered before use by iter-0 barrier)
    {
        const float* vsrc = v + (size_t)c * E_;
        *(f32x4*)&Vs[t * 8]     = *(const f32x4*)&vsrc[t * 8];
        *(f32x4*)&Vs[t * 8 + 4] = *(const f32x4*)&vsrc[t * 8 + 4];
    }

    f32x4 acc[4][4];
#pragma unroll
    for (int mt = 0; mt < 4; ++mt)
#pragma unroll
        for (int nt = 0; nt < 4; ++nt) acc[mt][nt] = (f32x4){0.f, 0.f, 0.f, 0.f};
    f32x4 y_acc[4];
#pragma unroll
    for (int nt = 0; nt < 4; ++nt) y_acc[nt] = (f32x4){0.f, 0.f, 0.f, 0.f};

    const int lr = l >> 3;
    const int lg = (l & 7) ^ lr;
    // wave w stages X rows [w*32,+32) and W rows [w*32,+32), 4 DMA instrs each
    const _Float16* xsrc = xh + (size_t)(b0 + w * 32 + lr) * E_ + lg * 8;
    const _Float16* wsrc = Wh + ((size_t)c * F_ + w * 32 + lr) * E_ + lg * 8;

    // epilogue constants hoisted (latency hidden under K-loop)
    float bi[4], ce[4];
#pragma unroll
    for (int nt = 0; nt < 4; ++nt) {
        int f = wn * 64 + nt * 16 + ln;
        bi[nt] = bias[c * F_ + f];
        ce[nt] = cent[c * F_ + f];
    }

    for (int k0 = 0; k0 < E_; k0 += 64) {
#pragma unroll
        for (int q = 0; q < 4; ++q)
            gl_lds16(xsrc + (size_t)q * 8 * E_ + k0, &Xs[(w * 4 + q) * 512]);
#pragma unroll
        for (int q = 0; q < 4; ++q)
            gl_lds16(wsrc + (size_t)q * 8 * E_ + k0, &Ws[(w * 4 + q) * 512]);
        __syncthreads();

#pragma unroll
        for (int kh = 0; kh < 2; ++kh) {
            const int g0 = (kh << 2) + quad;
            const int sw = (g0 ^ (ln & 7)) * 8;
            f16x8 av[4], bv[4];
#pragma unroll
            for (int mt = 0; mt < 4; ++mt)
                av[mt] = *(const f16x8*)&Xs[(wm * 64 + mt * 16 + ln) * 64 + sw];
#pragma unroll
            for (int nt = 0; nt < 4; ++nt)
                bv[nt] = *(const f16x8*)&Ws[(wn * 64 + nt * 16 + ln) * 64 + sw];
#pragma unroll
            for (int mt = 0; mt < 4; ++mt)
#pragma unroll
                for (int nt = 0; nt < 4; ++nt)
                    acc[mt][nt] = __builtin_amdgcn_mfma_f32_16x16x32_f16(
                        av[mt], bv[nt], acc[mt][nt], 0, 0, 0);

            // ---- y += W v (round-5 verified): vf = v-window in B col 0
            f16x8 vf;
#pragma unroll
            for (int j = 0; j < 8; ++j) vf[j] = (_Float16)0.0f;
            if (ln == 0) {
                const float* vp = &Vs[k0 + kh * 32 + quad * 8];
                const f32x4 a  = *(const f32x4*)vp;
                const f32x4 bq = *(const f32x4*)(vp + 4);
                vf[0] = (_Float16)a[0];  vf[1] = (_Float16)a[1];
                vf[2] = (_Float16)a[2];  vf[3] = (_Float16)a[3];
                vf[4] = (_Float16)bq[0]; vf[5] = (_Float16)bq[1];
                vf[6] = (_Float16)bq[2]; vf[7] = (_Float16)bq[3];
            }
#pragma unroll
            for (int nt = 0; nt < 4; ++nt)
                y_acc[nt] = __builtin_amdgcn_mfma_f32_16x16x32_f16(
                    bv[nt], vf, y_acc[nt], 0, 0, 0);
        }
        __syncthreads();
    }

    // ---- sigma: y lives in col 0 of y_acc (D: col=ln, row=quad*4+r)
    if (wm == 0 && ln == 0) {
#pragma unroll
        for (int nt = 0; nt < 4; ++nt)
#pragma unroll
            for (int r = 0; r < 4; ++r)
                ys[wn * 64 + nt * 16 + quad * 4 + r] = y_acc[nt][r];
    }
    __syncthreads();
    if (t < 128) {
        float yf  = ys[t];
        float nvp = u[(size_t)c * F_ + t] * yf;
        float tsp = yf * yf;
        for (int off = 32; off; off >>= 1) {
            nvp += __shfl_down(nvp, off, 64);
            tsp += __shfl_down(tsp, off, 64);
        }
        if (l == 0) { red2[w][0] = nvp; red2[w][1] = tsp; }
    }
    __syncthreads();
    if (t == 0) s_rsig = sqrtf((red2[0][0] + red2[1][0]) / (red2[0][1] + red2[1][1]));
    __syncthreads();
    const float rsigma = s_rsig;

    float* red = (float*)&Xs[0];        // [128][2] floats, post-loop reuse

#pragma unroll
    for (int mt = 0; mt < 4; ++mt) {
#pragma unroll
        for (int r = 0; r < 4; ++r) {
            float part = 0.f;
#pragma unroll
            for (int nt = 0; nt < 4; ++nt) {
                float z = fmaf(acc[mt][nt][r], rsigma, bi[nt]);
                float d = ce[nt] - z;
                part = fmaf(d, d, part);
            }
            part += __shfl_xor(part, 1, 64);
            part += __shfl_xor(part, 2, 64);
            part += __shfl_xor(part, 4, 64);
            part += __shfl_xor(part, 8, 64);
            if (ln == 0) {
                int m = wm * 64 + mt * 16 + quad * 4 + r;
                red[m * 2 + wn] = part;
            }
        }
    }
    __syncthreads();
    if (t < 128) {
        float d2 = red[t * 2] + red[t * 2 + 1];
        out[(size_t)(b0 + t) * C_ + c] = expf(-0.5f * d2);
    }
}

extern "C" void kernel_launch(void* const* d_in, const int* in_sizes, int n_in,
                              void* d_out, int out_size, void* d_ws, size_t ws_size,
                              hipStream_t stream) {
    const float* x  = (const float*)d_in[0];
    const float* W  = (const float*)d_in[1];
    const float* b  = (const float*)d_in[2];
    const float* u  = (const float*)d_in[3];
    const float* cc = (const float*)d_in[4];
    float* out = (float*)d_out;

    // workspace layout (all 16B aligned)
    char* ws = (char*)d_ws;
    _Float16* Wh = (_Float16*)ws;                                // 52,428,800 B
    _Float16* xh = (_Float16*)(ws + (size_t)C_ * F_ * E_ * 2);   //  2,097,152 B
    float*    v  = (float*)(ws + (size_t)C_ * F_ * E_ * 2 + (size_t)B_ * E_ * 2); // 819,200 B

    k_conv<<<432, 256, 0, stream>>>(W, Wh, x, xh, u, v);

    k_main<<<416, 256, 0, stream>>>(xh, Wh, b, cc, u, v, out);
}

// Round 10
// 209.553 us; speedup vs baseline: 1.0257x; 1.0257x over previous
//
#include <hip/hip_runtime.h>
#include <math.h>

#define B_ 512
#define C_ 100
#define E_ 2048
#define F_ 128
#define NCHUNK 16
#define CHUNKW 128   // k-width per gram block

typedef _Float16 f16x8 __attribute__((ext_vector_type(8)));
typedef float    f32x4 __attribute__((ext_vector_type(4)));

#define AS1q __attribute__((address_space(1)))
#define AS3q __attribute__((address_space(3)))

// async global->LDS DMA, 16 B per lane; LDS dest = wave-uniform base + lane*16
__device__ __forceinline__ void gl_lds16(const void* g, void* lds_base) {
    __builtin_amdgcn_global_load_lds((const AS1q void*)g, (AS3q void*)lds_base, 16, 0, 0);
}

// ---------------- kernel 1: W fp32 -> Wh fp16 conversion + y = W(W^T u) matvecs
// blocks 0..1599: (c = b>>4, chunk = b&15), k-window = chunk*128 +: 128.
//   fp32 W --DMA--> LDS (swizzled). Per 64-col iter:
//     A1: v[e] = sum_f W[f,e]*u[f]   (column sums; block holds all 128 f-rows)
//     conv: LDS fp32 -> fp16 -> Wh   (row registers kept)
//     A2: y_chunk[f] += row_f . v    (from the same registers)
//   ychunks[chunk][c][f] = y_chunk.  sum over chunks in k_main = W(W^T u) = G u.
//   MEASURED at its HBM stream floor (~29 us; r9's zero-LDS redesign was the
//   same speed — conflicts/barriers hide under HBM latency). r5 lesson: do not
//   fuse the GEMM here (4x re-staging).
// blocks 1600..1631: x fp32 -> fp16 xh.
__global__ __launch_bounds__(256, 4)
void k_gram(const float* __restrict__ W, _Float16* __restrict__ Wh,
            const float* __restrict__ x, _Float16* __restrict__ xh,
            const float* __restrict__ u, float* __restrict__ ychunks) {
    const int b = blockIdx.x;
    const int t = threadIdx.x;

    if (b >= 1600) {   // ---- x conversion
        const size_t base = (size_t)(b - 1600) * 32768 + t * 8;
#pragma unroll
        for (int it = 0; it < 16; ++it) {
            const size_t idx = base + (size_t)it * 2048;
            float4 a  = *(const float4*)(x + idx);
            float4 bb = *(const float4*)(x + idx + 4);
            f16x8 h;
            h[0] = (_Float16)a.x;  h[1] = (_Float16)a.y;  h[2] = (_Float16)a.z;  h[3] = (_Float16)a.w;
            h[4] = (_Float16)bb.x; h[5] = (_Float16)bb.y; h[6] = (_Float16)bb.z; h[7] = (_Float16)bb.w;
            *(f16x8*)(xh + idx) = h;
        }
        return;
    }

    const int c     = b >> 4;
    const int chunk = b & 15;
    const int w = t >> 6;
    const int l = t & 63;
    const int lrow4 = l >> 4, cs = l & 15;

    __shared__ float Ts[128 * 64];   // 32 KB swizzled fp32 tile
    __shared__ float vs[64];         // v[e] for current 64-col window
    __shared__ float us[128];        // u[f] for this class
    __shared__ float yred[256];      // per-thread y partials

    const float* wbase = W + (size_t)c * F_ * E_ + chunk * CHUNKW;

    // conversion-side constants: thread owns row cr, floats [cb, cb+32)
    const int cr = t >> 1, cb = (t & 1) * 32;
    _Float16* wdst = Wh + ((size_t)c * F_ + cr) * E_ + chunk * CHUNKW + cb;

    if (t < 128) us[t] = u[(size_t)c * F_ + t];

    // A1 assignment: column e = t>>2 (0..63), f-range [(t&3)*32, +32)
    const int ae = t >> 2;
    const int af = (t & 3) * 32;
    const int gch = ae >> 2, el = ae & 3;

    float yacc = 0.f;

#pragma unroll
    for (int it = 0; it < CHUNKW / 64; ++it) {
        const int k0 = it * 64;
#pragma unroll
        for (int qq = 0; qq < 8; ++qq) {
            const int q   = w * 8 + qq;
            const int r   = q * 4 + lrow4;
            const int off = ((cs ^ (r & 15)) << 2);
            gl_lds16(wbase + (size_t)r * E_ + k0 + off, &Ts[q * 256]);
        }
        __syncthreads();   // tile ready (also publishes us[] on it=0)

        // ---- A1: v[e] = sum_f W[f,e] * u[f]  (swizzle-aware column reads)
        {
            float p = 0.f;
#pragma unroll
            for (int j = 0; j < 32; ++j) {
                const int f = af + j;
                p = fmaf(Ts[(f << 6) + (((gch ^ (f & 15)) << 2) | el)], us[f], p);
            }
            p += __shfl_xor(p, 1, 64);
            p += __shfl_xor(p, 2, 64);
            if ((t & 3) == 0) vs[ae] = p;
        }

        // ---- conv: row cr fp32 -> fp16 -> Wh (registers reused by A2)
        f32x4 cv[8];
#pragma unroll
        for (int j = 0; j < 8; ++j) {
            const int g = (cb >> 2) + j;
            cv[j] = *(const f32x4*)&Ts[cr * 64 + ((g ^ (cr & 15)) << 2)];
        }
#pragma unroll
        for (int j = 0; j < 4; ++j) {
            f16x8 h;
            h[0] = (_Float16)cv[2*j][0];   h[1] = (_Float16)cv[2*j][1];
            h[2] = (_Float16)cv[2*j][2];   h[3] = (_Float16)cv[2*j][3];
            h[4] = (_Float16)cv[2*j+1][0]; h[5] = (_Float16)cv[2*j+1][1];
            h[6] = (_Float16)cv[2*j+1][2]; h[7] = (_Float16)cv[2*j+1][3];
            *(f16x8*)(wdst + k0 + j * 8) = h;
        }
        __syncthreads();   // vs ready; Ts fully consumed (next DMA may overwrite)

        // ---- A2: y_chunk[cr] partial += row(cr, cols cb..cb+32) . vs
#pragma unroll
        for (int j = 0; j < 8; ++j) {
            const f32x4 vv = *(const f32x4*)&vs[cb + j * 4];
            yacc = fmaf(cv[j][0], vv[0], yacc);
            yacc = fmaf(cv[j][1], vv[1], yacc);
            yacc = fmaf(cv[j][2], vv[2], yacc);
            yacc = fmaf(cv[j][3], vv[3], yacc);
        }
    }

    yred[cr * 2 + (t & 1)] = yacc;
    __syncthreads();
    if (t < 128)
        ychunks[((size_t)chunk * C_ + c) * F_ + t] = yred[t * 2] + yred[t * 2 + 1];
}

// ---------------- kernel 2: fused fp16 MFMA GEMM + dist2 + exp, rsig inline
// 1-D grid 416, XCD-aware mapping (the session's one measured win, -6 us):
//   xcd = bid&7, slot = bid>>3, c = xcd*13 + slot>>2, b-tile = slot&3.
// 4 sibling b-tiles of a class share one XCD, adjacent dispatch -> the 524 KB
// Wh slice streams through ONE L2. Measured structural ceiling for this
// 2-barrier shape (~41 us): dbuf (r6), counted vmcnt (r7), BM=64 (r4),
// X-from-global (r1), full fusion (r5), y-MFMA in-loop (r9) all null/negative.
// LDS reads conflict-free (SQ_LDS_BANK_CONFLICT = 0).
// block 256 = 4 waves (2x2); M=128, N=128, BK=64; X+W both DMA-staged.
__global__ __launch_bounds__(256, 3)
void k_main(const _Float16* __restrict__ xh, const _Float16* __restrict__ Wh,
            const float* __restrict__ bias, const float* __restrict__ cent,
            const float* __restrict__ u, const float* __restrict__ ychunks,
            float* __restrict__ out) {
    const int bid  = blockIdx.x;
    const int xcd  = bid & 7;
    const int slot = bid >> 3;
    const int c    = xcd * 13 + (slot >> 2);
    if (c >= C_) return;                       // uniform early-out (16 blocks)
    const int b0 = (slot & 3) * 128;

    const int t  = threadIdx.x;
    const int w  = t >> 6;
    const int l  = t & 63;
    const int wm = w & 1, wn = w >> 1;
    const int ln = l & 15, quad = l >> 4;

    __shared__ _Float16 Xs[128 * 64];   // 16 KB
    __shared__ _Float16 Ws[128 * 64];   // 16 KB
    __shared__ float red2[2][2];
    __shared__ float s_rsig;

    // ---- inline rsig = sqrt(u.y / y.y),  y[f] = sum_chunk ychunks[chunk][c][f]
    if (t < 128) {
        float yf = 0.f;
#pragma unroll
        for (int ch = 0; ch < NCHUNK; ++ch)
            yf += ychunks[((size_t)ch * C_ + c) * F_ + t];
        float nvp = u[(size_t)c * F_ + t] * yf;
        float tsp = yf * yf;
        for (int off = 32; off; off >>= 1) {
            nvp += __shfl_down(nvp, off, 64);
            tsp += __shfl_down(tsp, off, 64);
        }
        if (l == 0) { red2[w][0] = nvp; red2[w][1] = tsp; }
    }
    __syncthreads();
    if (t == 0) s_rsig = sqrtf((red2[0][0] + red2[1][0]) / (red2[0][1] + red2[1][1]));
    // s_rsig visibility guaranteed by the K-loop barriers below.

    f32x4 acc[4][4];
#pragma unroll
    for (int mt = 0; mt < 4; ++mt)
#pragma unroll
        for (int nt = 0; nt < 4; ++nt) acc[mt][nt] = (f32x4){0.f, 0.f, 0.f, 0.f};

    const int lr = l >> 3;
    const int lg = (l & 7) ^ lr;
    // wave w stages X rows [w*32,+32) and W rows [w*32,+32), 4 DMA instrs each
    const _Float16* xsrc = xh + (size_t)(b0 + w * 32 + lr) * E_ + lg * 8;
    const _Float16* wsrc = Wh + ((size_t)c * F_ + w * 32 + lr) * E_ + lg * 8;

    for (int k0 = 0; k0 < E_; k0 += 64) {
#pragma unroll
        for (int q = 0; q < 4; ++q)
            gl_lds16(xsrc + (size_t)q * 8 * E_ + k0, &Xs[(w * 4 + q) * 512]);
#pragma unroll
        for (int q = 0; q < 4; ++q)
            gl_lds16(wsrc + (size_t)q * 8 * E_ + k0, &Ws[(w * 4 + q) * 512]);
        __syncthreads();

#pragma unroll
        for (int kk = 0; kk < 64; kk += 32) {
            const int g0 = (kk >> 3) + quad;
            const int sw = (g0 ^ (ln & 7)) * 8;
            f16x8 av[4], bv[4];
#pragma unroll
            for (int mt = 0; mt < 4; ++mt)
                av[mt] = *(const f16x8*)&Xs[(wm * 64 + mt * 16 + ln) * 64 + sw];
#pragma unroll
            for (int nt = 0; nt < 4; ++nt)
                bv[nt] = *(const f16x8*)&Ws[(wn * 64 + nt * 16 + ln) * 64 + sw];
#pragma unroll
            for (int mt = 0; mt < 4; ++mt)
#pragma unroll
                for (int nt = 0; nt < 4; ++nt)
                    acc[mt][nt] = __builtin_amdgcn_mfma_f32_16x16x32_f16(
                        av[mt], bv[nt], acc[mt][nt], 0, 0, 0);
        }
        __syncthreads();
    }

    const float rsigma = s_rsig;

    float bi[4], ce[4];
#pragma unroll
    for (int nt = 0; nt < 4; ++nt) {
        int f = wn * 64 + nt * 16 + ln;
        bi[nt] = bias[c * F_ + f];
        ce[nt] = cent[c * F_ + f];
    }

    float* red = (float*)&Xs[0];        // [128][2] floats, post-barrier reuse

#pragma unroll
    for (int mt = 0; mt < 4; ++mt) {
#pragma unroll
        for (int r = 0; r < 4; ++r) {
            float part = 0.f;
#pragma unroll
            for (int nt = 0; nt < 4; ++nt) {
                float z = fmaf(acc[mt][nt][r], rsigma, bi[nt]);
                float d = ce[nt] - z;
                part = fmaf(d, d, part);
            }
            part += __shfl_xor(part, 1, 64);
            part += __shfl_xor(part, 2, 64);
            part += __shfl_xor(part, 4, 64);
            part += __shfl_xor(part, 8, 64);
            if (ln == 0) {
                int m = wm * 64 + mt * 16 + quad * 4 + r;
                red[m * 2 + wn] = part;
            }
        }
    }
    __syncthreads();
    if (t < 128) {
        float d2 = red[t * 2] + red[t * 2 + 1];
        out[(size_t)(b0 + t) * C_ + c] = expf(-0.5f * d2);
    }
}

extern "C" void kernel_launch(void* const* d_in, const int* in_sizes, int n_in,
                              void* d_out, int out_size, void* d_ws, size_t ws_size,
                              hipStream_t stream) {
    const float* x  = (const float*)d_in[0];
    const float* W  = (const float*)d_in[1];
    const float* b  = (const float*)d_in[2];
    const float* u  = (const float*)d_in[3];
    const float* cc = (const float*)d_in[4];
    float* out = (float*)d_out;

    // workspace layout (all 16B aligned)
    char* ws = (char*)d_ws;
    _Float16* Wh      = (_Float16*)ws;                                // 52,428,800 B
    _Float16* xh      = (_Float16*)(ws + (size_t)C_ * F_ * E_ * 2);   //  2,097,152 B
    float*    ychunks = (float*)(ws + (size_t)C_ * F_ * E_ * 2 + (size_t)B_ * E_ * 2); // 819,200 B

    k_gram<<<1632, 256, 0, stream>>>(W, Wh, x, xh, u, ychunks);

    k_main<<<416, 256, 0, stream>>>(xh, Wh, b, cc, u, ychunks, out);
}